// Round 1
// 671.614 us; speedup vs baseline: 1.2972x; 1.2972x over previous
//
#include <hip/hip_runtime.h>
#include <hip/hip_bf16.h>

typedef __bf16 bf16x8 __attribute__((ext_vector_type(8)));
typedef __bf16 bf16x4 __attribute__((ext_vector_type(4)));
typedef float f32x4 __attribute__((ext_vector_type(4)));

// ---------------- dtype-robust load helpers ----------------
__device__ __forceinline__ float getf(const void* p, size_t i, int isf32){
  return isf32 ? ((const float*)p)[i]
               : __bfloat162float(((const __hip_bfloat16*)p)[i]);
}
__device__ __forceinline__ int getedge(const void* p, long long idx, int is64, int n){
  long long v = is64 ? ((const long long*)p)[idx] : (long long)((const int*)p)[idx];
  v = v < 0 ? 0 : (v >= n ? (long long)(n - 1) : v);
  return (int)v;
}

__device__ __forceinline__ float bfly_sum(float v){
#pragma unroll
  for (int m = 32; m > 0; m >>= 1) v += __shfl_xor(v, m, 64);
  return v;
}

// ---------------- runtime dtype detection ----------------
__global__ __launch_bounds__(256) void detect_kernel(const void* x, const void* ei,
                                                     int* flags){
  __shared__ int cnt_sane, cnt_odd;
  int t = threadIdx.x;
  if (t == 0){ cnt_sane = 0; cnt_odd = 0; }
  __syncthreads();
  int sane = 0;
  for (int i = t; i < 4096; i += 256){
    float v = __bfloat162float(((const __hip_bfloat16*)x)[i]);
    if (fabsf(v) < 16.f) sane++;
  }
  atomicAdd(&cnt_sane, sane);
  int odd = 0;
  for (int i = t; i < 512; i += 256){
    if (((const int*)ei)[2 * i + 1] != 0) odd++;
  }
  atomicAdd(&cnt_odd, odd);
  __syncthreads();
  if (t == 0){
    flags[0] = (cnt_sane < 3900) ? 1 : 0;  // 1 => float inputs are fp32
    flags[1] = (cnt_odd == 0) ? 1 : 0;     // 1 => edge_index is int64
  }
}

// ---------------- graph bucketing ----------------
__global__ __launch_bounds__(256) void count_kernel(const void* __restrict__ ei, long long E,
                                                    int n, const int* __restrict__ flags,
                                                    int* __restrict__ cnt){
  int i = blockIdx.x * blockDim.x + threadIdx.x;
  if (i < E){
    int d = getedge(ei, E + i, flags[1], n);
    atomicAdd(&cnt[d], 1);
  }
}

__global__ __launch_bounds__(1024) void scan_kernel(const int* __restrict__ cnt, int* __restrict__ off,
                                                    int* __restrict__ pos, int n){
  __shared__ int wsum[16];
  __shared__ int carry_s;
  int tid = threadIdx.x, lane = tid & 63, wv = tid >> 6;
  if (tid == 0) carry_s = 0;
  __syncthreads();
  for (int base = 0; base < n; base += 1024){
    int i = base + tid;
    int v = (i < n) ? cnt[i] : 0;
    int s = v;
#pragma unroll
    for (int o = 1; o < 64; o <<= 1){ int t = __shfl_up(s, o, 64); if (lane >= o) s += t; }
    if (lane == 63) wsum[wv] = s;
    __syncthreads();
    int wo = 0;
    for (int w = 0; w < wv; w++) wo += wsum[w];
    int carry = carry_s;
    int excl = carry + wo + s - v;
    if (i < n){ off[i] = excl; pos[i] = excl; }
    __syncthreads();
    if (tid == 0){
      int tot = 0;
      for (int w = 0; w < 16; w++) tot += wsum[w];
      carry_s = carry + tot;
    }
    __syncthreads();
  }
  if (tid == 0) off[n] = carry_s;
}

__global__ __launch_bounds__(256) void fill_kernel(const void* __restrict__ ei, long long E,
                                                   int n, const int* __restrict__ flags,
                                                   int* __restrict__ pos, int* __restrict__ bsrc,
                                                   int* __restrict__ bdst){
  int i = blockIdx.x * blockDim.x + threadIdx.x;
  if (i < E){
    int d = getedge(ei, E + i, flags[1], n);
    int s = getedge(ei, i, flags[1], n);
    int p = atomicAdd(&pos[d], 1);
    bsrc[p] = s;
    bdst[p] = d;
  }
}

// ---------------- weight pre-transpose: Bt[N][K] (bf16) = W[K][N] ----------------
__global__ __launch_bounds__(256) void transpose_w_kernel(const void* __restrict__ W,
    const int* __restrict__ flags, __hip_bfloat16* __restrict__ Bt, int K, int N)
{
  int f0 = flags[0];
  int o = blockIdx.x * 256 + threadIdx.x;
  if (o < K * N){
    int nn = o / K, kk = o - nn * K;
    Bt[o] = __float2bfloat16(getf(W, (size_t)kk * N + nn, f0));
  }
}

// ---------------- LDS-free direct-fragment MFMA GEMM ----------------
// C[M,N] = A[M,K] @ Bt^T  (Bt is [N][K] bf16). Block = 128 rows x 128 cols, 4 waves.
// Wave w owns rows [bx*128 + w*32, +32). Fragments loaded straight from global:
// lane(q=lane>>4, mi=lane&15) A-frag = A[row = base+mt*16+mi][k0+q*8 .. +7] (16B contig),
// B-frag = Bt[col = bn+nt*16+mi][k0+q*8 .. +7]. 4 q-lanes cover one full 64B line.
__device__ __forceinline__ bf16x8 pk8(f32x4 u, f32x4 w){
  bf16x8 r;
  r[0] = (__bf16)u.x; r[1] = (__bf16)u.y; r[2] = (__bf16)u.z; r[3] = (__bf16)u.w;
  r[4] = (__bf16)w.x; r[5] = (__bf16)w.y; r[6] = (__bf16)w.z; r[7] = (__bf16)w.w;
  return r;
}

template<int AMODE, bool OUTF, bool OUTB, bool RELU, bool BIAS>
__global__ __launch_bounds__(256) void gemm_direct_kernel(
    const void* __restrict__ A, const __hip_bfloat16* __restrict__ Bt,
    const void* __restrict__ bias, const int* __restrict__ flags,
    float* __restrict__ Cf, __hip_bfloat16* __restrict__ Cb,
    int M, int N, int K)
{
  const int f0 = flags[0];
  const bool af32 = (AMODE == 1) && (f0 != 0);
  int t = threadIdx.x;
  int wave = t >> 6, lane = t & 63;
  int q = lane >> 4, mi = lane & 15;
  int bm = blockIdx.x * 128 + wave * 32;
  int bn = blockIdx.y * 128;

  // clamped rows for loads (stores are guarded; OOB lanes read row M-1 harmlessly)
  int r0 = min(bm + mi, M - 1);
  int r1 = min(bm + 16 + mi, M - 1);

  f32x4 acc[2][8] = {};

  if (af32){
    const float* Af = (const float*)A;
    const float* p0 = Af + (size_t)r0 * K + q * 8;
    const float* p1 = Af + (size_t)r1 * K + q * 8;
#pragma unroll 2
    for (int k0 = 0; k0 < K; k0 += 32){
      f32x4 u0 = *(const f32x4*)(p0 + k0);
      f32x4 w0 = *(const f32x4*)(p0 + k0 + 4);
      f32x4 u1 = *(const f32x4*)(p1 + k0);
      f32x4 w1 = *(const f32x4*)(p1 + k0 + 4);
      bf16x8 a0 = pk8(u0, w0);
      bf16x8 a1 = pk8(u1, w1);
#pragma unroll
      for (int nt = 0; nt < 8; nt++){
        bf16x8 b = *(const bf16x8*)(Bt + (size_t)(bn + nt * 16 + mi) * K + k0 + q * 8);
        acc[0][nt] = __builtin_amdgcn_mfma_f32_16x16x32_bf16(a0, b, acc[0][nt], 0, 0, 0);
        acc[1][nt] = __builtin_amdgcn_mfma_f32_16x16x32_bf16(a1, b, acc[1][nt], 0, 0, 0);
      }
    }
  } else {
    const __hip_bfloat16* Ab = (const __hip_bfloat16*)A;
    const __hip_bfloat16* p0 = Ab + (size_t)r0 * K + q * 8;
    const __hip_bfloat16* p1 = Ab + (size_t)r1 * K + q * 8;
#pragma unroll 2
    for (int k0 = 0; k0 < K; k0 += 32){
      bf16x8 a0 = *(const bf16x8*)(p0 + k0);
      bf16x8 a1 = *(const bf16x8*)(p1 + k0);
#pragma unroll
      for (int nt = 0; nt < 8; nt++){
        bf16x8 b = *(const bf16x8*)(Bt + (size_t)(bn + nt * 16 + mi) * K + k0 + q * 8);
        acc[0][nt] = __builtin_amdgcn_mfma_f32_16x16x32_bf16(a0, b, acc[0][nt], 0, 0, 0);
        acc[1][nt] = __builtin_amdgcn_mfma_f32_16x16x32_bf16(a1, b, acc[1][nt], 0, 0, 0);
      }
    }
  }

  // epilogue: C row = bm + mt*16 + q*4 + r, col = bn + nt*16 + mi
  float bv[8];
  if (BIAS){
#pragma unroll
    for (int nt = 0; nt < 8; nt++) bv[nt] = getf(bias, bn + nt * 16 + mi, f0);
  }
#pragma unroll
  for (int mt = 0; mt < 2; mt++){
#pragma unroll
    for (int r = 0; r < 4; r++){
      int row = bm + mt * 16 + q * 4 + r;
      if (row < M){
#pragma unroll
        for (int nt = 0; nt < 8; nt++){
          int col = bn + nt * 16 + mi;
          float v = acc[mt][nt][r];
          if (BIAS) v += bv[nt];
          if (RELU) v = fmaxf(v, 0.f);
          size_t idx = (size_t)row * N + col;
          if (OUTF) Cf[idx] = v;
          if (OUTB) Cb[idx] = __float2bfloat16(v);
        }
      }
    }
  }
}

// ---------------- attention logits ----------------
__global__ __launch_bounds__(256) void al0_kernel(const __hip_bfloat16* __restrict__ xw,
    const void* __restrict__ a_s, const void* __restrict__ a_d, const int* __restrict__ flags,
    float* __restrict__ als, float* __restrict__ ald, int n)
{
  int f0 = flags[0];
  int i = blockIdx.x, t = threadIdx.x;
  int h = t >> 6, lane = t & 63;
  float v = __bfloat162float(xw[(size_t)i * 256 + t]);
  float ps = v * getf(a_s, t, f0);
  float pd = v * getf(a_d, t, f0);
  ps = bfly_sum(ps); pd = bfly_sum(pd);
  if (lane == 0){ als[(size_t)i * 4 + h] = ps; ald[(size_t)i * 4 + h] = pd; }
}

__global__ __launch_bounds__(128) void al1_kernel(const __hip_bfloat16* __restrict__ xw,
    const void* __restrict__ a_s, const void* __restrict__ a_d, const int* __restrict__ flags,
    float* __restrict__ als, float* __restrict__ ald, int n)
{
  __shared__ float rs[2], rd[2];
  int f0 = flags[0];
  int i = blockIdx.x, t = threadIdx.x;
  int wv = t >> 6, lane = t & 63;
  float v = __bfloat162float(xw[(size_t)i * 128 + t]);
  float ps = v * getf(a_s, t, f0);
  float pd = v * getf(a_d, t, f0);
  ps = bfly_sum(ps); pd = bfly_sum(pd);
  if (lane == 0){ rs[wv] = ps; rd[wv] = pd; }
  __syncthreads();
  if (t == 0){ als[i] = rs[0] + rs[1]; ald[i] = rd[0] + rd[1]; }
}

// ---------------- edge weight kernels: w = exp(leaky(als[src]+ald[dst])) ----------------
__global__ __launch_bounds__(256) void wq0_kernel(const float* __restrict__ als,
    const float* __restrict__ ald, const int* __restrict__ bsrc, const int* __restrict__ bdst,
    f32x4* __restrict__ wq, int E)
{
  int p = blockIdx.x * 256 + threadIdx.x;
  if (p < E){
    int s = bsrc[p], d = bdst[p];
    f32x4 a = ((const f32x4*)als)[s];
    f32x4 b = ((const f32x4*)ald)[d];
    f32x4 w;
#pragma unroll
    for (int k = 0; k < 4; k++){
      float e = a[k] + b[k];
      e = (e > 0.f) ? e : 0.2f * e;
      w[k] = __expf(e);
    }
    wq[p] = w;
  }
}

__global__ __launch_bounds__(256) void wq1_kernel(const float* __restrict__ als,
    const float* __restrict__ ald, const int* __restrict__ bsrc, const int* __restrict__ bdst,
    float* __restrict__ wq, int E)
{
  int p = blockIdx.x * 256 + threadIdx.x;
  if (p < E){
    float e = als[bsrc[p]] + ald[bdst[p]];
    e = (e > 0.f) ? e : 0.2f * e;
    wq[p] = __expf(e);
  }
}

#define FMA8(U, W) do { \
  macc[0] += (W) * __uint_as_float((U).x << 16); \
  macc[1] += (W) * __uint_as_float((U).x & 0xffff0000u); \
  macc[2] += (W) * __uint_as_float((U).y << 16); \
  macc[3] += (W) * __uint_as_float((U).y & 0xffff0000u); \
  macc[4] += (W) * __uint_as_float((U).z << 16); \
  macc[5] += (W) * __uint_as_float((U).z & 0xffff0000u); \
  macc[6] += (W) * __uint_as_float((U).w << 16); \
  macc[7] += (W) * __uint_as_float((U).w & 0xffff0000u); \
} while (0)

// ---------------- gather0: block-per-node, precomputed weights, on-the-fly denominator ----------------
// now writes h1 as bf16 (consumed only by GEMM2 which would re-round anyway)
__global__ __launch_bounds__(256) void gather0_kernel(
    const __hip_bfloat16* __restrict__ xw, const float* __restrict__ als, const float* __restrict__ ald,
    const int* __restrict__ bsrc, const float* __restrict__ wq, const int* __restrict__ off,
    const void* __restrict__ bias, const void* __restrict__ gamma,
    const void* __restrict__ beta, const int* __restrict__ flags,
    const float* __restrict__ resf, __hip_bfloat16* __restrict__ outb, int n)
{
  int f0 = flags[0];
  int i = blockIdx.x;
  int t = threadIdx.x, wv = t >> 6, lane = t & 63;
  int e0 = off[i];
  int jend = off[i + 1];
  int ch0 = (lane & 31) * 8;
  int headc = (lane & 31) >> 3;
  int esub = lane >> 5;               // 0,1
  const __hip_bfloat16* xp = xw + ch0;

  __shared__ float sp[4][264];
  __shared__ float slh[4][4];
  __shared__ float s_red[4];

  float macc[8] = {};
  float wacc = 0.f;

  // self-loop (added once: wave 0, esub 0)
  float selfe = als[(size_t)i * 4 + headc] + ald[(size_t)i * 4 + headc];
  selfe = (selfe > 0.f) ? selfe : 0.2f * selfe;
  float eself = __expf(selfe);
  if (wv == 0 && esub == 0){
    uint4 u = *(const uint4*)(xp + (size_t)i * 256);
    FMA8(u, eself);
  }

  // edges: slot = wv*2+esub (0..7), stride 8, 4-deep pipeline
  int slot = wv * 2 + esub;
  for (int j = e0 + slot; j < jend; j += 32){
    int jA = j, jB = j + 8, jC = j + 16, jD = j + 24;
    int cA = jA, cB = min(jB, jend - 1), cC = min(jC, jend - 1), cD = min(jD, jend - 1);
    int sA = bsrc[cA], sB_ = bsrc[cB], sC = bsrc[cC], sD = bsrc[cD];
    float WA = wq[(size_t)cA * 4 + headc];
    float WB = wq[(size_t)cB * 4 + headc];
    float WC = wq[(size_t)cC * 4 + headc];
    float WD = wq[(size_t)cD * 4 + headc];
    uint4 UA = *(const uint4*)(xp + (size_t)sA * 256);
    uint4 UB = *(const uint4*)(xp + (size_t)sB_ * 256);
    uint4 UC = *(const uint4*)(xp + (size_t)sC * 256);
    uint4 UD = *(const uint4*)(xp + (size_t)sD * 256);
    WB = (jB < jend) ? WB : 0.f;
    WC = (jC < jend) ? WC : 0.f;
    WD = (jD < jend) ? WD : 0.f;
    wacc += WA + WB + WC + WD;
    FMA8(UA, WA); FMA8(UB, WB); FMA8(UC, WC); FMA8(UD, WD);
  }

  // fold esub halves (lane ^ 32 holds same channels / same head)
#pragma unroll
  for (int k = 0; k < 8; k++) macc[k] += __shfl_xor(macc[k], 32, 64);
  wacc += __shfl_xor(wacc, 32, 64);

  if (lane < 32){
    *(f32x4*)&sp[wv][ch0]     = (f32x4){macc[0], macc[1], macc[2], macc[3]};
    *(f32x4*)&sp[wv][ch0 + 4] = (f32x4){macc[4], macc[5], macc[6], macc[7]};
    if ((lane & 7) == 0) slh[wv][headc] = wacc;
  }
  __syncthreads();

  // thread t = channel t
  int hh = t >> 6;
  float selft = als[(size_t)i * 4 + hh] + ald[(size_t)i * 4 + hh];
  selft = (selft > 0.f) ? selft : 0.2f * selft;
  float lsum = slh[0][hh] + slh[1][hh] + slh[2][hh] + slh[3][hh] + __expf(selft);
  float v = (sp[0][t] + sp[1][t] + sp[2][t] + sp[3][t]) / lsum + getf(bias, t, f0);

  // LayerNorm over 256 channels
  float s1 = bfly_sum(v);
  if (lane == 0) s_red[wv] = s1;
  __syncthreads();
  float mu = (s_red[0] + s_red[1] + s_red[2] + s_red[3]) * (1.f / 256.f);
  __syncthreads();
  float d = v - mu;
  float s2 = bfly_sum(d * d);
  if (lane == 0) s_red[wv] = s2;
  __syncthreads();
  float var = (s_red[0] + s_red[1] + s_red[2] + s_red[3]) * (1.f / 256.f);
  float y = d * rsqrtf(var + 1e-5f) * getf(gamma, t, f0) + getf(beta, t, f0);
  y = fmaxf(y + resf[(size_t)i * 256 + t], 0.f);
  outb[(size_t)i * 256 + t] = __float2bfloat16(y);
}

// ---------------- gather1: block-per-node, H=1, C=128 (bf16 out) ----------------
__global__ __launch_bounds__(256) void gather1_kernel(
    const __hip_bfloat16* __restrict__ xw, const float* __restrict__ als, const float* __restrict__ ald,
    const int* __restrict__ bsrc, const float* __restrict__ wq, const int* __restrict__ off,
    const void* __restrict__ bias, const void* __restrict__ gamma,
    const void* __restrict__ beta, const int* __restrict__ flags,
    __hip_bfloat16* __restrict__ outb, int n)
{
  int f0 = flags[0];
  int i = blockIdx.x;
  int t = threadIdx.x, wv = t >> 6, lane = t & 63;
  int e0 = off[i];
  int jend = off[i + 1];
  int ch0 = (lane & 15) * 8;
  int esub = lane >> 4;               // 0..3
  const __hip_bfloat16* xp = xw + ch0;

  __shared__ float sp[4][136];
  __shared__ float slh[4];
  __shared__ float s_red[2];

  float macc[8] = {};
  float wacc = 0.f;

  float selfe = als[i] + ald[i];
  selfe = (selfe > 0.f) ? selfe : 0.2f * selfe;
  float eself = __expf(selfe);
  if (wv == 0 && esub == 0){
    uint4 u = *(const uint4*)(xp + (size_t)i * 128);
    FMA8(u, eself);
  }

  // slot = wv*4+esub (0..15), stride 16, 2-deep pipeline
  int slot = wv * 4 + esub;
  for (int j = e0 + slot; j < jend; j += 32){
    int jA = j, jB = j + 16;
    int cB = min(jB, jend - 1);
    int sA = bsrc[jA], sB_ = bsrc[cB];
    float WA = wq[jA];
    float WB = wq[cB];
    uint4 UA = *(const uint4*)(xp + (size_t)sA * 128);
    uint4 UB = *(const uint4*)(xp + (size_t)sB_ * 128);
    WB = (jB < jend) ? WB : 0.f;
    wacc += WA + WB;
    FMA8(UA, WA); FMA8(UB, WB);
  }

  // fold esub groups: xor16 then xor32
#pragma unroll
  for (int k = 0; k < 8; k++){
    macc[k] += __shfl_xor(macc[k], 16, 64);
    macc[k] += __shfl_xor(macc[k], 32, 64);
  }
  wacc += __shfl_xor(wacc, 16, 64);
  wacc += __shfl_xor(wacc, 32, 64);

  if (lane < 16){
    *(f32x4*)&sp[wv][ch0]     = (f32x4){macc[0], macc[1], macc[2], macc[3]};
    *(f32x4*)&sp[wv][ch0 + 4] = (f32x4){macc[4], macc[5], macc[6], macc[7]};
    if (lane == 0) slh[wv] = wacc;
  }
  __syncthreads();

  if (t < 128){
    float lsum = slh[0] + slh[1] + slh[2] + slh[3] + eself;
    float v = (sp[0][t] + sp[1][t] + sp[2][t] + sp[3][t]) / lsum + getf(bias, t, f0);
    float s1 = bfly_sum(v);
    if (lane == 0) s_red[wv] = s1;
    __syncthreads();
    float mu = (s_red[0] + s_red[1]) * (1.f / 128.f);
    __syncthreads();
    float d = v - mu;
    float s2 = bfly_sum(d * d);
    if (lane == 0) s_red[wv] = s2;
    __syncthreads();
    float var = (s_red[0] + s_red[1]) * (1.f / 128.f);
    float y = d * rsqrtf(var + 1e-5f) * getf(gamma, t, f0) + getf(beta, t, f0);
    outb[(size_t)i * 128 + t] = __float2bfloat16(y);
  } else {
    __syncthreads(); __syncthreads(); __syncthreads();
  }
}

// ---------------- row L2-normalize ----------------
__global__ __launch_bounds__(128) void norm_kernel(const float* __restrict__ in,
                                                   float* __restrict__ outp, int n)
{
  __shared__ float sred[2];
  int i = blockIdx.x, t = threadIdx.x, wv = t >> 6, lane = t & 63;
  float v = in[(size_t)i * 128 + t];
  float ss = bfly_sum(v * v);
  if (lane == 0) sred[wv] = ss;
  __syncthreads();
  float inv = 1.f / fmaxf(sqrtf(sred[0] + sred[1]), 1e-12f);
  outp[(size_t)i * 128 + t] = v * inv;
}

// ---------------- launch ----------------
extern "C" void kernel_launch(void* const* d_in, const int* in_sizes, int n_in,
                              void* d_out, int out_size, void* d_ws, size_t ws_size,
                              hipStream_t stream)
{
  const void* x   = d_in[0];
  const void* ei  = d_in[1];
  const void* Wp  = d_in[2];
  const void* bp  = d_in[3];
  const void* W0  = d_in[4];
  const void* as0 = d_in[5];
  const void* ad0 = d_in[6];
  const void* b0  = d_in[7];
  const void* W1  = d_in[8];
  const void* as1 = d_in[9];
  const void* ad1 = d_in[10];
  const void* b1  = d_in[11];
  const void* g0  = d_in[12];
  const void* be0 = d_in[13];
  const void* g1  = d_in[14];
  const void* be1 = d_in[15];
  const void* Wo  = d_in[16];
  const void* bo  = d_in[17];
  float* outp = (float*)d_out;

  const int n = in_sizes[0] / 256;   // 50000
  const int E = in_sizes[1] / 2;     // 800000

  char* w = (char*)d_ws;
  size_t SZ = (size_t)n * 256 * sizeof(float);
  // h_f32: h (fp32, residual) -> prenorm (n x 128 fp32)
  float* h_f32 = (float*)w;
  // h_bf: h (bf16) -> h1 (bf16) -> h2 (n x 128 bf16)
  __hip_bfloat16* h_bf = (__hip_bfloat16*)(w + SZ);
  // xw_bf: xw0 (n x 256 bf16) -> xw1 (n x 128 bf16)
  __hip_bfloat16* xw_bf = (__hip_bfloat16*)(w + SZ + SZ / 2);
  char* p = w + 2 * SZ;
  int* flags = (int*)p; p += 64;
  float* als0 = (float*)p; p += (size_t)n * 4 * sizeof(float);
  float* ald0 = (float*)p; p += (size_t)n * 4 * sizeof(float);
  float* als1 = (float*)p; p += (size_t)n * sizeof(float);
  float* ald1 = (float*)p; p += (size_t)n * sizeof(float);
  int* cnt  = (int*)p; p += (size_t)n * sizeof(int);
  int* offb = (int*)p; p += (size_t)(n + 1) * sizeof(int) + 4;
  int* pos  = (int*)p; p += (size_t)n * sizeof(int);
  int* bsrc = (int*)p; p += (size_t)E * sizeof(int);
  int* bdst = (int*)p; p += (size_t)E * sizeof(int);
  p = (char*)(((uintptr_t)p + 15) & ~(uintptr_t)15);
  float* wqbuf = (float*)p; p += ((size_t)E + 64) * 4 * sizeof(float);  // reused: [E][4] or [E]
  __hip_bfloat16* bt_p = (__hip_bfloat16*)p; p += (size_t)256 * 256 * 2;
  __hip_bfloat16* bt_0 = (__hip_bfloat16*)p; p += (size_t)256 * 256 * 2;
  __hip_bfloat16* bt_1 = (__hip_bfloat16*)p; p += (size_t)128 * 256 * 2;
  __hip_bfloat16* bt_o = (__hip_bfloat16*)p; p += (size_t)128 * 128 * 2;

  detect_kernel<<<1, 256, 0, stream>>>(x, ei, flags);

  // weight pre-transposes (tiny, L2-resident afterwards)
  transpose_w_kernel<<<(256 * 256 + 255) / 256, 256, 0, stream>>>(Wp, flags, bt_p, 256, 256);
  transpose_w_kernel<<<(256 * 256 + 255) / 256, 256, 0, stream>>>(W0, flags, bt_0, 256, 256);
  transpose_w_kernel<<<(256 * 128 + 255) / 256, 256, 0, stream>>>(W1, flags, bt_1, 256, 128);
  transpose_w_kernel<<<(128 * 128 + 255) / 256, 256, 0, stream>>>(Wo, flags, bt_o, 128, 128);

  hipMemsetAsync(cnt, 0, (size_t)n * sizeof(int), stream);
  count_kernel<<<(E + 255) / 256, 256, 0, stream>>>(ei, E, n, flags, cnt);
  scan_kernel<<<1, 1024, 0, stream>>>(cnt, offb, pos, n);
  fill_kernel<<<(E + 255) / 256, 256, 0, stream>>>(ei, E, n, flags, pos, bsrc, bdst);

  int gm = (n + 127) / 128;
  int ge = (E + 255) / 256;
  // h = relu(x @ Wp + bp): fp32 out (residual) + bf16 out (GEMM1 input)
  gemm_direct_kernel<1, true, true, true, true><<<dim3(gm, 2), 256, 0, stream>>>(
      x, bt_p, bp, flags, h_f32, h_bf, n, 256, 256);
  // xw0 = h @ W0 (bf16 out)
  gemm_direct_kernel<0, false, true, false, false><<<dim3(gm, 2), 256, 0, stream>>>(
      h_bf, bt_0, nullptr, flags, nullptr, xw_bf, n, 256, 256);
  al0_kernel<<<n, 256, 0, stream>>>(xw_bf, as0, ad0, flags, als0, ald0, n);
  wq0_kernel<<<ge, 256, 0, stream>>>(als0, ald0, bsrc, bdst, (f32x4*)wqbuf, E);
  // layer-0 aggregate + b0 + LN + residual + relu -> h1 (bf16, into h_bf)
  gather0_kernel<<<n, 256, 0, stream>>>(xw_bf, als0, ald0, bsrc, wqbuf, offb, b0, g0, be0,
                                        flags, h_f32, h_bf, n);
  // xw1 = h1 @ W1 (bf16 out, n x 128)
  gemm_direct_kernel<0, false, true, false, false><<<dim3(gm, 1), 256, 0, stream>>>(
      h_bf, bt_1, nullptr, flags, nullptr, xw_bf, n, 128, 256);
  al1_kernel<<<n, 128, 0, stream>>>(xw_bf, as1, ad1, flags, als1, ald1, n);
  wq1_kernel<<<ge, 256, 0, stream>>>(als1, ald1, bsrc, bdst, wqbuf, E);
  // layer-1 aggregate + b1 + LN -> h2 (bf16, into h_bf)
  gather1_kernel<<<n, 256, 0, stream>>>(xw_bf, als1, ald1, bsrc, wqbuf, offb, b1, g1, be1,
                                        flags, h_bf, n);
  // prenorm = h2 @ Wo + bo (fp32, into h_f32)
  gemm_direct_kernel<0, true, false, false, true><<<dim3(gm, 1), 256, 0, stream>>>(
      h_bf, bt_o, bo, flags, h_f32, nullptr, n, 128, 128);
  // out = row-normalize
  norm_kernel<<<n, 128, 0, stream>>>(h_f32, outp, n);
}

// Round 2
// 595.279 us; speedup vs baseline: 1.4635x; 1.1282x over previous
//
#include <hip/hip_runtime.h>
#include <hip/hip_bf16.h>

typedef __bf16 bf16x8 __attribute__((ext_vector_type(8)));
typedef __bf16 bf16x4 __attribute__((ext_vector_type(4)));
typedef __bf16 bf16x2 __attribute__((ext_vector_type(2)));
typedef float f32x4 __attribute__((ext_vector_type(4)));

// ---------------- dtype-robust load helpers ----------------
__device__ __forceinline__ float getf(const void* p, size_t i, int isf32){
  return isf32 ? ((const float*)p)[i]
               : __bfloat162float(((const __hip_bfloat16*)p)[i]);
}
__device__ __forceinline__ int getedge(const void* p, long long idx, int is64, int n){
  long long v = is64 ? ((const long long*)p)[idx] : (long long)((const int*)p)[idx];
  v = v < 0 ? 0 : (v >= n ? (long long)(n - 1) : v);
  return (int)v;
}

__device__ __forceinline__ float bfly_sum(float v){
#pragma unroll
  for (int m = 32; m > 0; m >>= 1) v += __shfl_xor(v, m, 64);
  return v;
}

// ---------------- runtime dtype detection ----------------
__global__ __launch_bounds__(256) void detect_kernel(const void* x, const void* ei,
                                                     int* flags){
  __shared__ int cnt_sane, cnt_odd;
  int t = threadIdx.x;
  if (t == 0){ cnt_sane = 0; cnt_odd = 0; }
  __syncthreads();
  int sane = 0;
  for (int i = t; i < 4096; i += 256){
    float v = __bfloat162float(((const __hip_bfloat16*)x)[i]);
    if (fabsf(v) < 16.f) sane++;
  }
  atomicAdd(&cnt_sane, sane);
  int odd = 0;
  for (int i = t; i < 512; i += 256){
    if (((const int*)ei)[2 * i + 1] != 0) odd++;
  }
  atomicAdd(&cnt_odd, odd);
  __syncthreads();
  if (t == 0){
    flags[0] = (cnt_sane < 3900) ? 1 : 0;  // 1 => float inputs are fp32
    flags[1] = (cnt_odd == 0) ? 1 : 0;     // 1 => edge_index is int64
  }
}

// ---------------- graph bucketing ----------------
__global__ __launch_bounds__(256) void count_kernel(const void* __restrict__ ei, long long E,
                                                    int n, const int* __restrict__ flags,
                                                    int* __restrict__ cnt){
  int i = blockIdx.x * blockDim.x + threadIdx.x;
  if (i < E){
    int d = getedge(ei, E + i, flags[1], n);
    atomicAdd(&cnt[d], 1);
  }
}

__global__ __launch_bounds__(1024) void scan_kernel(const int* __restrict__ cnt, int* __restrict__ off,
                                                    int* __restrict__ pos, int n){
  __shared__ int wsum[16];
  __shared__ int carry_s;
  int tid = threadIdx.x, lane = tid & 63, wv = tid >> 6;
  if (tid == 0) carry_s = 0;
  __syncthreads();
  for (int base = 0; base < n; base += 1024){
    int i = base + tid;
    int v = (i < n) ? cnt[i] : 0;
    int s = v;
#pragma unroll
    for (int o = 1; o < 64; o <<= 1){ int t = __shfl_up(s, o, 64); if (lane >= o) s += t; }
    if (lane == 63) wsum[wv] = s;
    __syncthreads();
    int wo = 0;
    for (int w = 0; w < wv; w++) wo += wsum[w];
    int carry = carry_s;
    int excl = carry + wo + s - v;
    if (i < n){ off[i] = excl; pos[i] = excl; }
    __syncthreads();
    if (tid == 0){
      int tot = 0;
      for (int w = 0; w < 16; w++) tot += wsum[w];
      carry_s = carry + tot;
    }
    __syncthreads();
  }
  if (tid == 0) off[n] = carry_s;
}

__global__ __launch_bounds__(256) void fill_kernel(const void* __restrict__ ei, long long E,
                                                   int n, const int* __restrict__ flags,
                                                   int* __restrict__ pos, int* __restrict__ bsrc,
                                                   int* __restrict__ bdst){
  int i = blockIdx.x * blockDim.x + threadIdx.x;
  if (i < E){
    int d = getedge(ei, E + i, flags[1], n);
    int s = getedge(ei, i, flags[1], n);
    int p = atomicAdd(&pos[d], 1);
    bsrc[p] = s;
    bdst[p] = d;
  }
}

// ---------------- weight pre-transpose: Bt[N][K] (bf16) = W[K][N] ----------------
__global__ __launch_bounds__(256) void transpose_w_kernel(const void* __restrict__ W,
    const int* __restrict__ flags, __hip_bfloat16* __restrict__ Bt, int K, int N)
{
  int f0 = flags[0];
  int o = blockIdx.x * 256 + threadIdx.x;
  if (o < K * N){
    int nn = o / K, kk = o - nn * K;
    Bt[o] = __float2bfloat16(getf(W, (size_t)kk * N + nn, f0));
  }
}

// ---------------- LDS-free direct-fragment MFMA GEMM ----------------
// C[M,N] = A[M,K] @ Bt^T  (Bt is [N][K] bf16). Block = 128 rows x 128 cols, 4 waves.
__device__ __forceinline__ bf16x8 pk8(f32x4 u, f32x4 w){
  bf16x8 r;
  r[0] = (__bf16)u.x; r[1] = (__bf16)u.y; r[2] = (__bf16)u.z; r[3] = (__bf16)u.w;
  r[4] = (__bf16)w.x; r[5] = (__bf16)w.y; r[6] = (__bf16)w.z; r[7] = (__bf16)w.w;
  return r;
}

template<int AMODE, bool OUTF, bool OUTB, bool RELU, bool BIAS, bool NORM>
__global__ __launch_bounds__(256) void gemm_direct_kernel(
    const void* __restrict__ A, const __hip_bfloat16* __restrict__ Bt,
    const void* __restrict__ bias, const int* __restrict__ flags,
    float* __restrict__ Cf, __hip_bfloat16* __restrict__ Cb,
    int M, int N, int K)
{
  const int f0 = flags[0];
  const bool af32 = (AMODE == 1) && (f0 != 0);
  int t = threadIdx.x;
  int wave = t >> 6, lane = t & 63;
  int q = lane >> 4, mi = lane & 15;
  int bm = blockIdx.x * 128 + wave * 32;
  int bn = blockIdx.y * 128;

  int r0 = min(bm + mi, M - 1);
  int r1 = min(bm + 16 + mi, M - 1);

  f32x4 acc[2][8] = {};

  if (af32){
    const float* Af = (const float*)A;
    const float* p0 = Af + (size_t)r0 * K + q * 8;
    const float* p1 = Af + (size_t)r1 * K + q * 8;
#pragma unroll 2
    for (int k0 = 0; k0 < K; k0 += 32){
      f32x4 u0 = *(const f32x4*)(p0 + k0);
      f32x4 w0 = *(const f32x4*)(p0 + k0 + 4);
      f32x4 u1 = *(const f32x4*)(p1 + k0);
      f32x4 w1 = *(const f32x4*)(p1 + k0 + 4);
      bf16x8 a0 = pk8(u0, w0);
      bf16x8 a1 = pk8(u1, w1);
#pragma unroll
      for (int nt = 0; nt < 8; nt++){
        bf16x8 b = *(const bf16x8*)(Bt + (size_t)(bn + nt * 16 + mi) * K + k0 + q * 8);
        acc[0][nt] = __builtin_amdgcn_mfma_f32_16x16x32_bf16(a0, b, acc[0][nt], 0, 0, 0);
        acc[1][nt] = __builtin_amdgcn_mfma_f32_16x16x32_bf16(a1, b, acc[1][nt], 0, 0, 0);
      }
    }
  } else {
    const __hip_bfloat16* Ab = (const __hip_bfloat16*)A;
    const __hip_bfloat16* p0 = Ab + (size_t)r0 * K + q * 8;
    const __hip_bfloat16* p1 = Ab + (size_t)r1 * K + q * 8;
#pragma unroll 2
    for (int k0 = 0; k0 < K; k0 += 32){
      bf16x8 a0 = *(const bf16x8*)(p0 + k0);
      bf16x8 a1 = *(const bf16x8*)(p1 + k0);
#pragma unroll
      for (int nt = 0; nt < 8; nt++){
        bf16x8 b = *(const bf16x8*)(Bt + (size_t)(bn + nt * 16 + mi) * K + k0 + q * 8);
        acc[0][nt] = __builtin_amdgcn_mfma_f32_16x16x32_bf16(a0, b, acc[0][nt], 0, 0, 0);
        acc[1][nt] = __builtin_amdgcn_mfma_f32_16x16x32_bf16(a1, b, acc[1][nt], 0, 0, 0);
      }
    }
  }

  float bv[8];
  if (BIAS){
#pragma unroll
    for (int nt = 0; nt < 8; nt++) bv[nt] = getf(bias, bn + nt * 16 + mi, f0);
  }
#pragma unroll
  for (int mt = 0; mt < 2; mt++){
#pragma unroll
    for (int r = 0; r < 4; r++){
      int row = bm + mt * 16 + q * 4 + r;
      float vv[8];
#pragma unroll
      for (int nt = 0; nt < 8; nt++){
        float v = acc[mt][nt][r];
        if (BIAS) v += bv[nt];
        if (RELU) v = fmaxf(v, 0.f);
        vv[nt] = v;
      }
      if (NORM){
        // row is identical across the 16 lanes sharing q; its 128 cols live in
        // this 16-lane group (8 nt x 16 mi). Reduce sumsq in-group, normalize.
        float ss = 0.f;
#pragma unroll
        for (int nt = 0; nt < 8; nt++) ss += vv[nt] * vv[nt];
        ss += __shfl_xor(ss, 1, 64);
        ss += __shfl_xor(ss, 2, 64);
        ss += __shfl_xor(ss, 4, 64);
        ss += __shfl_xor(ss, 8, 64);
        float inv = 1.f / fmaxf(sqrtf(ss), 1e-12f);
#pragma unroll
        for (int nt = 0; nt < 8; nt++) vv[nt] *= inv;
      }
      if (row < M){
#pragma unroll
        for (int nt = 0; nt < 8; nt++){
          int col = bn + nt * 16 + mi;
          size_t idx = (size_t)row * N + col;
          if (OUTF) Cf[idx] = vv[nt];
          if (OUTB) Cb[idx] = __float2bfloat16(vv[nt]);
        }
      }
    }
  }
}

// ---------------- attention logits (wave-per-node) ----------------
__global__ __launch_bounds__(256) void al0_kernel(const __hip_bfloat16* __restrict__ xw,
    const void* __restrict__ a_s, const void* __restrict__ a_d, const int* __restrict__ flags,
    float* __restrict__ als, float* __restrict__ ald, int n)
{
  int f0 = flags[0];
  int t = threadIdx.x, wv = t >> 6, lane = t & 63;
  int i = blockIdx.x * 4 + wv;
  if (i >= n) return;
  int ch = lane * 4;
  uint2 u = *(const uint2*)(xw + (size_t)i * 256 + ch);
  float x0 = __uint_as_float(u.x << 16);
  float x1 = __uint_as_float(u.x & 0xffff0000u);
  float x2 = __uint_as_float(u.y << 16);
  float x3 = __uint_as_float(u.y & 0xffff0000u);
  float ps = x0 * getf(a_s, ch + 0, f0) + x1 * getf(a_s, ch + 1, f0)
           + x2 * getf(a_s, ch + 2, f0) + x3 * getf(a_s, ch + 3, f0);
  float pd = x0 * getf(a_d, ch + 0, f0) + x1 * getf(a_d, ch + 1, f0)
           + x2 * getf(a_d, ch + 2, f0) + x3 * getf(a_d, ch + 3, f0);
  // reduce within 16-lane head group
  ps += __shfl_xor(ps, 1, 64); pd += __shfl_xor(pd, 1, 64);
  ps += __shfl_xor(ps, 2, 64); pd += __shfl_xor(pd, 2, 64);
  ps += __shfl_xor(ps, 4, 64); pd += __shfl_xor(pd, 4, 64);
  ps += __shfl_xor(ps, 8, 64); pd += __shfl_xor(pd, 8, 64);
  if ((lane & 15) == 0){
    int h = lane >> 4;
    als[(size_t)i * 4 + h] = ps;
    ald[(size_t)i * 4 + h] = pd;
  }
}

__global__ __launch_bounds__(256) void al1_kernel(const __hip_bfloat16* __restrict__ xw,
    const void* __restrict__ a_s, const void* __restrict__ a_d, const int* __restrict__ flags,
    float* __restrict__ als, float* __restrict__ ald, int n)
{
  int f0 = flags[0];
  int t = threadIdx.x, wv = t >> 6, lane = t & 63;
  int i = blockIdx.x * 4 + wv;
  if (i >= n) return;
  int ch = lane * 2;
  unsigned u = *(const unsigned*)(xw + (size_t)i * 128 + ch);
  float x0 = __uint_as_float(u << 16);
  float x1 = __uint_as_float(u & 0xffff0000u);
  float ps = x0 * getf(a_s, ch + 0, f0) + x1 * getf(a_s, ch + 1, f0);
  float pd = x0 * getf(a_d, ch + 0, f0) + x1 * getf(a_d, ch + 1, f0);
  ps = bfly_sum(ps); pd = bfly_sum(pd);
  if (lane == 0){ als[i] = ps; ald[i] = pd; }
}

// ---------------- edge weight kernels: w = exp(leaky(als[src]+ald[dst])) ----------------
__global__ __launch_bounds__(256) void wq0_kernel(const float* __restrict__ als,
    const float* __restrict__ ald, const int* __restrict__ bsrc, const int* __restrict__ bdst,
    f32x4* __restrict__ wq, int E)
{
  int p = blockIdx.x * 256 + threadIdx.x;
  if (p < E){
    int s = bsrc[p], d = bdst[p];
    f32x4 a = ((const f32x4*)als)[s];
    f32x4 b = ((const f32x4*)ald)[d];
    f32x4 w;
#pragma unroll
    for (int k = 0; k < 4; k++){
      float e = a[k] + b[k];
      e = (e > 0.f) ? e : 0.2f * e;
      w[k] = __expf(e);
    }
    wq[p] = w;
  }
}

__global__ __launch_bounds__(256) void wq1_kernel(const float* __restrict__ als,
    const float* __restrict__ ald, const int* __restrict__ bsrc, const int* __restrict__ bdst,
    float* __restrict__ wq, int E)
{
  int p = blockIdx.x * 256 + threadIdx.x;
  if (p < E){
    float e = als[bsrc[p]] + ald[bdst[p]];
    e = (e > 0.f) ? e : 0.2f * e;
    wq[p] = __expf(e);
  }
}

#define FMA4(U, W) do { \
  m0 += (W) * __uint_as_float((U).x << 16); \
  m1 += (W) * __uint_as_float((U).x & 0xffff0000u); \
  m2 += (W) * __uint_as_float((U).y << 16); \
  m3 += (W) * __uint_as_float((U).y & 0xffff0000u); \
} while (0)

// ---------------- gather0: WAVE-per-node, H=4, C=64 ----------------
// lane owns 4 channels (ch = lane*4); head = lane>>4. Denominator accumulates
// per-lane (identical within head group) -> no reductions, no LDS, no barriers.
__global__ __launch_bounds__(256) void gather0_kernel(
    const __hip_bfloat16* __restrict__ xw, const float* __restrict__ als, const float* __restrict__ ald,
    const int* __restrict__ bsrc, const float* __restrict__ wq, const int* __restrict__ off,
    const void* __restrict__ bias, const void* __restrict__ gamma,
    const void* __restrict__ beta, const int* __restrict__ flags,
    const float* __restrict__ resf, __hip_bfloat16* __restrict__ outb, int n)
{
  int f0 = flags[0];
  int t = threadIdx.x, wv = t >> 6, lane = t & 63;
  int i = blockIdx.x * 4 + wv;
  if (i >= n) return;
  int head = lane >> 4;
  int ch = lane * 4;
  int e0 = off[i], jend = off[i + 1];

  float m0 = 0.f, m1 = 0.f, m2 = 0.f, m3 = 0.f;

  // self loop
  float se = als[(size_t)i * 4 + head] + ald[(size_t)i * 4 + head];
  se = (se > 0.f) ? se : 0.2f * se;
  float eself = __expf(se);
  {
    uint2 u = *(const uint2*)(xw + (size_t)i * 256 + ch);
    FMA4(u, eself);
  }
  float wacc = eself;

  // main loop: full quads, no clamping
  int j = e0;
  for (; j + 3 < jend; j += 4){
    int s0 = bsrc[j], s1 = bsrc[j + 1], s2 = bsrc[j + 2], s3 = bsrc[j + 3];
    float w0 = wq[(size_t)j * 4 + head];
    float w1 = wq[(size_t)(j + 1) * 4 + head];
    float w2 = wq[(size_t)(j + 2) * 4 + head];
    float w3 = wq[(size_t)(j + 3) * 4 + head];
    uint2 U0 = *(const uint2*)(xw + (size_t)s0 * 256 + ch);
    uint2 U1 = *(const uint2*)(xw + (size_t)s1 * 256 + ch);
    uint2 U2 = *(const uint2*)(xw + (size_t)s2 * 256 + ch);
    uint2 U3 = *(const uint2*)(xw + (size_t)s3 * 256 + ch);
    wacc += w0 + w1 + w2 + w3;
    FMA4(U0, w0); FMA4(U1, w1); FMA4(U2, w2); FMA4(U3, w3);
  }
  // tail (<=3 edges), wave-uniform trip count
  for (; j < jend; j++){
    int s0 = bsrc[j];
    float w0 = wq[(size_t)j * 4 + head];
    uint2 U0 = *(const uint2*)(xw + (size_t)s0 * 256 + ch);
    wacc += w0;
    FMA4(U0, w0);
  }

  // softmax denominator + bias
  float rl = 1.f / wacc;
  float v0 = m0 * rl + getf(bias, ch + 0, f0);
  float v1 = m1 * rl + getf(bias, ch + 1, f0);
  float v2 = m2 * rl + getf(bias, ch + 2, f0);
  float v3 = m3 * rl + getf(bias, ch + 3, f0);

  // in-wave LayerNorm over 256 channels
  float mu = bfly_sum(v0 + v1 + v2 + v3) * (1.f / 256.f);
  float d0 = v0 - mu, d1 = v1 - mu, d2 = v2 - mu, d3 = v3 - mu;
  float var = bfly_sum(d0 * d0 + d1 * d1 + d2 * d2 + d3 * d3) * (1.f / 256.f);
  float rs = rsqrtf(var + 1e-5f);

  f32x4 res = *(const f32x4*)(resf + (size_t)i * 256 + ch);
  float y0 = fmaxf(d0 * rs * getf(gamma, ch + 0, f0) + getf(beta, ch + 0, f0) + res.x, 0.f);
  float y1 = fmaxf(d1 * rs * getf(gamma, ch + 1, f0) + getf(beta, ch + 1, f0) + res.y, 0.f);
  float y2 = fmaxf(d2 * rs * getf(gamma, ch + 2, f0) + getf(beta, ch + 2, f0) + res.z, 0.f);
  float y3 = fmaxf(d3 * rs * getf(gamma, ch + 3, f0) + getf(beta, ch + 3, f0) + res.w, 0.f);

  bf16x4 o;
  o[0] = (__bf16)y0; o[1] = (__bf16)y1; o[2] = (__bf16)y2; o[3] = (__bf16)y3;
  *(bf16x4*)(outb + (size_t)i * 256 + ch) = o;
}

// ---------------- gather1: WAVE-per-node, H=1, C=128 ----------------
#define FMA2(U, W) do { \
  m0 += (W) * __uint_as_float((U) << 16); \
  m1 += (W) * __uint_as_float((U) & 0xffff0000u); \
} while (0)

__global__ __launch_bounds__(256) void gather1_kernel(
    const __hip_bfloat16* __restrict__ xw, const float* __restrict__ als, const float* __restrict__ ald,
    const int* __restrict__ bsrc, const float* __restrict__ wq, const int* __restrict__ off,
    const void* __restrict__ bias, const void* __restrict__ gamma,
    const void* __restrict__ beta, const int* __restrict__ flags,
    __hip_bfloat16* __restrict__ outb, int n)
{
  int f0 = flags[0];
  int t = threadIdx.x, wv = t >> 6, lane = t & 63;
  int i = blockIdx.x * 4 + wv;
  if (i >= n) return;
  int ch = lane * 2;
  int e0 = off[i], jend = off[i + 1];

  float m0 = 0.f, m1 = 0.f;

  float se = als[i] + ald[i];
  se = (se > 0.f) ? se : 0.2f * se;
  float eself = __expf(se);
  {
    unsigned u = *(const unsigned*)(xw + (size_t)i * 128 + ch);
    FMA2(u, eself);
  }
  float wacc = eself;

  int j = e0;
  for (; j + 3 < jend; j += 4){
    int s0 = bsrc[j], s1 = bsrc[j + 1], s2 = bsrc[j + 2], s3 = bsrc[j + 3];
    float w0 = wq[j], w1 = wq[j + 1], w2 = wq[j + 2], w3 = wq[j + 3];
    unsigned U0 = *(const unsigned*)(xw + (size_t)s0 * 128 + ch);
    unsigned U1 = *(const unsigned*)(xw + (size_t)s1 * 128 + ch);
    unsigned U2 = *(const unsigned*)(xw + (size_t)s2 * 128 + ch);
    unsigned U3 = *(const unsigned*)(xw + (size_t)s3 * 128 + ch);
    wacc += w0 + w1 + w2 + w3;
    FMA2(U0, w0); FMA2(U1, w1); FMA2(U2, w2); FMA2(U3, w3);
  }
  for (; j < jend; j++){
    int s0 = bsrc[j];
    float w0 = wq[j];
    unsigned U0 = *(const unsigned*)(xw + (size_t)s0 * 128 + ch);
    wacc += w0;
    FMA2(U0, w0);
  }

  float rl = 1.f / wacc;
  float v0 = m0 * rl + getf(bias, ch + 0, f0);
  float v1 = m1 * rl + getf(bias, ch + 1, f0);

  float mu = bfly_sum(v0 + v1) * (1.f / 128.f);
  float d0 = v0 - mu, d1 = v1 - mu;
  float var = bfly_sum(d0 * d0 + d1 * d1) * (1.f / 128.f);
  float rs = rsqrtf(var + 1e-5f);

  float y0 = d0 * rs * getf(gamma, ch + 0, f0) + getf(beta, ch + 0, f0);
  float y1 = d1 * rs * getf(gamma, ch + 1, f0) + getf(beta, ch + 1, f0);

  bf16x2 o;
  o[0] = (__bf16)y0; o[1] = (__bf16)y1;
  *(bf16x2*)(outb + (size_t)i * 128 + ch) = o;
}

// ---------------- launch ----------------
extern "C" void kernel_launch(void* const* d_in, const int* in_sizes, int n_in,
                              void* d_out, int out_size, void* d_ws, size_t ws_size,
                              hipStream_t stream)
{
  const void* x   = d_in[0];
  const void* ei  = d_in[1];
  const void* Wp  = d_in[2];
  const void* bp  = d_in[3];
  const void* W0  = d_in[4];
  const void* as0 = d_in[5];
  const void* ad0 = d_in[6];
  const void* b0  = d_in[7];
  const void* W1  = d_in[8];
  const void* as1 = d_in[9];
  const void* ad1 = d_in[10];
  const void* b1  = d_in[11];
  const void* g0  = d_in[12];
  const void* be0 = d_in[13];
  const void* g1  = d_in[14];
  const void* be1 = d_in[15];
  const void* Wo  = d_in[16];
  const void* bo  = d_in[17];
  float* outp = (float*)d_out;

  const int n = in_sizes[0] / 256;   // 50000
  const int E = in_sizes[1] / 2;     // 800000

  char* w = (char*)d_ws;
  size_t SZ = (size_t)n * 256 * sizeof(float);
  float* h_f32 = (float*)w;                                   // h (fp32 residual)
  __hip_bfloat16* h_bf = (__hip_bfloat16*)(w + SZ);           // h -> h1 -> h2 (bf16)
  __hip_bfloat16* xw_bf = (__hip_bfloat16*)(w + SZ + SZ / 2); // xw0 -> xw1 (bf16)
  char* p = w + 2 * SZ;
  int* flags = (int*)p; p += 64;
  float* als0 = (float*)p; p += (size_t)n * 4 * sizeof(float);
  float* ald0 = (float*)p; p += (size_t)n * 4 * sizeof(float);
  float* als1 = (float*)p; p += (size_t)n * sizeof(float);
  float* ald1 = (float*)p; p += (size_t)n * sizeof(float);
  int* cnt  = (int*)p; p += (size_t)n * sizeof(int);
  int* offb = (int*)p; p += (size_t)(n + 1) * sizeof(int) + 4;
  int* pos  = (int*)p; p += (size_t)n * sizeof(int);
  int* bsrc = (int*)p; p += (size_t)E * sizeof(int);
  int* bdst = (int*)p; p += (size_t)E * sizeof(int);
  p = (char*)(((uintptr_t)p + 15) & ~(uintptr_t)15);
  float* wqbuf = (float*)p; p += ((size_t)E + 64) * 4 * sizeof(float);
  __hip_bfloat16* bt_p = (__hip_bfloat16*)p; p += (size_t)256 * 256 * 2;
  __hip_bfloat16* bt_0 = (__hip_bfloat16*)p; p += (size_t)256 * 256 * 2;
  __hip_bfloat16* bt_1 = (__hip_bfloat16*)p; p += (size_t)128 * 256 * 2;
  __hip_bfloat16* bt_o = (__hip_bfloat16*)p; p += (size_t)128 * 128 * 2;

  detect_kernel<<<1, 256, 0, stream>>>(x, ei, flags);

  transpose_w_kernel<<<(256 * 256 + 255) / 256, 256, 0, stream>>>(Wp, flags, bt_p, 256, 256);
  transpose_w_kernel<<<(256 * 256 + 255) / 256, 256, 0, stream>>>(W0, flags, bt_0, 256, 256);
  transpose_w_kernel<<<(256 * 128 + 255) / 256, 256, 0, stream>>>(W1, flags, bt_1, 256, 128);
  transpose_w_kernel<<<(128 * 128 + 255) / 256, 256, 0, stream>>>(Wo, flags, bt_o, 128, 128);

  hipMemsetAsync(cnt, 0, (size_t)n * sizeof(int), stream);
  count_kernel<<<(E + 255) / 256, 256, 0, stream>>>(ei, E, n, flags, cnt);
  scan_kernel<<<1, 1024, 0, stream>>>(cnt, offb, pos, n);
  fill_kernel<<<(E + 255) / 256, 256, 0, stream>>>(ei, E, n, flags, pos, bsrc, bdst);

  int gm = (n + 127) / 128;
  int ge = (E + 255) / 256;
  int gn4 = (n + 3) / 4;

  // h = relu(x @ Wp + bp): fp32 out (residual) + bf16 out
  gemm_direct_kernel<1, true, true, true, true, false><<<dim3(gm, 2), 256, 0, stream>>>(
      x, bt_p, bp, flags, h_f32, h_bf, n, 256, 256);
  // xw0 = h @ W0 (bf16 out)
  gemm_direct_kernel<0, false, true, false, false, false><<<dim3(gm, 2), 256, 0, stream>>>(
      h_bf, bt_0, nullptr, flags, nullptr, xw_bf, n, 256, 256);
  al0_kernel<<<gn4, 256, 0, stream>>>(xw_bf, as0, ad0, flags, als0, ald0, n);
  wq0_kernel<<<ge, 256, 0, stream>>>(als0, ald0, bsrc, bdst, (f32x4*)wqbuf, E);
  // layer-0 aggregate + b0 + LN + residual + relu -> h1 (bf16, into h_bf)
  gather0_kernel<<<gn4, 256, 0, stream>>>(xw_bf, als0, ald0, bsrc, wqbuf, offb, b0, g0, be0,
                                          flags, h_f32, h_bf, n);
  // xw1 = h1 @ W1 (bf16 out, n x 128)
  gemm_direct_kernel<0, false, true, false, false, false><<<dim3(gm, 1), 256, 0, stream>>>(
      h_bf, bt_1, nullptr, flags, nullptr, xw_bf, n, 128, 256);
  al1_kernel<<<gn4, 256, 0, stream>>>(xw_bf, as1, ad1, flags, als1, ald1, n);
  wq1_kernel<<<ge, 256, 0, stream>>>(als1, ald1, bsrc, bdst, wqbuf, E);
  // layer-1 aggregate + b1 + LN -> h2 (bf16, into h_bf)
  gather1_kernel<<<gn4, 256, 0, stream>>>(xw_bf, als1, ald1, bsrc, wqbuf, offb, b1, g1, be1,
                                          flags, h_bf, n);
  // out = l2normalize(h2 @ Wo + bo), fused epilogue, direct to output
  gemm_direct_kernel<0, true, false, false, true, true><<<dim3(gm, 1), 256, 0, stream>>>(
      h_bf, bt_o, bo, flags, outp, nullptr, n, 128, 128);
}

// Round 3
// 496.360 us; speedup vs baseline: 1.7552x; 1.1993x over previous
//
#include <hip/hip_runtime.h>
#include <hip/hip_bf16.h>

typedef __bf16 bf16x8 __attribute__((ext_vector_type(8)));
typedef __bf16 bf16x4 __attribute__((ext_vector_type(4)));
typedef __bf16 bf16x2 __attribute__((ext_vector_type(2)));
typedef float f32x4 __attribute__((ext_vector_type(4)));

// ---------------- dtype-robust load helpers ----------------
__device__ __forceinline__ float getf(const void* p, size_t i, int isf32){
  return isf32 ? ((const float*)p)[i]
               : __bfloat162float(((const __hip_bfloat16*)p)[i]);
}
__device__ __forceinline__ int getedge(const void* p, long long idx, int is64, int n){
  long long v = is64 ? ((const long long*)p)[idx] : (long long)((const int*)p)[idx];
  v = v < 0 ? 0 : (v >= n ? (long long)(n - 1) : v);
  return (int)v;
}

__device__ __forceinline__ float bfly_sum(float v){
#pragma unroll
  for (int m = 32; m > 0; m >>= 1) v += __shfl_xor(v, m, 64);
  return v;
}

// ---------------- runtime dtype detection ----------------
__global__ __launch_bounds__(256) void detect_kernel(const void* x, const void* ei,
                                                     int* flags){
  __shared__ int cnt_sane, cnt_odd;
  int t = threadIdx.x;
  if (t == 0){ cnt_sane = 0; cnt_odd = 0; }
  __syncthreads();
  int sane = 0;
  for (int i = t; i < 4096; i += 256){
    float v = __bfloat162float(((const __hip_bfloat16*)x)[i]);
    if (fabsf(v) < 16.f) sane++;
  }
  atomicAdd(&cnt_sane, sane);
  int odd = 0;
  for (int i = t; i < 512; i += 256){
    if (((const int*)ei)[2 * i + 1] != 0) odd++;
  }
  atomicAdd(&cnt_odd, odd);
  __syncthreads();
  if (t == 0){
    flags[0] = (cnt_sane < 3900) ? 1 : 0;  // 1 => float inputs are fp32
    flags[1] = (cnt_odd == 0) ? 1 : 0;     // 1 => edge_index is int64
  }
}

// ---------------- graph bucketing ----------------
__global__ __launch_bounds__(256) void count_kernel(const void* __restrict__ ei, long long E,
                                                    int n, const int* __restrict__ flags,
                                                    int* __restrict__ cnt){
  int i = blockIdx.x * blockDim.x + threadIdx.x;
  if (i < E){
    int d = getedge(ei, E + i, flags[1], n);
    atomicAdd(&cnt[d], 1);
  }
}

// 4x-vectorized single-block scan (13 iterations for n=50000)
__global__ __launch_bounds__(1024) void scan_kernel(const int* __restrict__ cnt, int* __restrict__ off,
                                                    int* __restrict__ pos, int n){
  __shared__ int wsum[16];
  __shared__ int carry_s;
  int tid = threadIdx.x, lane = tid & 63, wv = tid >> 6;
  if (tid == 0) carry_s = 0;
  __syncthreads();
  for (int base = 0; base < n; base += 4096){
    int i0 = base + tid * 4;
    int v0 = 0, v1 = 0, v2 = 0, v3 = 0;
    if (i0 + 3 < n){
      int4 q = *(const int4*)(cnt + i0);
      v0 = q.x; v1 = q.y; v2 = q.z; v3 = q.w;
    } else {
      if (i0 < n)     v0 = cnt[i0];
      if (i0 + 1 < n) v1 = cnt[i0 + 1];
      if (i0 + 2 < n) v2 = cnt[i0 + 2];
      if (i0 + 3 < n) v3 = cnt[i0 + 3];
    }
    int s4 = v0 + v1 + v2 + v3;
    int s = s4;
#pragma unroll
    for (int o = 1; o < 64; o <<= 1){ int t = __shfl_up(s, o, 64); if (lane >= o) s += t; }
    if (lane == 63) wsum[wv] = s;
    __syncthreads();
    int wo = 0;
    for (int w = 0; w < wv; w++) wo += wsum[w];
    int carry = carry_s;
    int e0 = carry + wo + s - s4;  // exclusive prefix for this thread's first elem
    if (i0 + 3 < n){
      int4 o4; o4.x = e0; o4.y = e0 + v0; o4.z = e0 + v0 + v1; o4.w = e0 + v0 + v1 + v2;
      *(int4*)(off + i0) = o4;
      *(int4*)(pos + i0) = o4;
    } else {
      if (i0 < n)     { off[i0] = e0;               pos[i0] = e0; }
      if (i0 + 1 < n) { off[i0+1] = e0+v0;          pos[i0+1] = e0+v0; }
      if (i0 + 2 < n) { off[i0+2] = e0+v0+v1;       pos[i0+2] = e0+v0+v1; }
      if (i0 + 3 < n) { off[i0+3] = e0+v0+v1+v2;    pos[i0+3] = e0+v0+v1+v2; }
    }
    __syncthreads();
    if (tid == 0){
      int tot = 0;
      for (int w = 0; w < 16; w++) tot += wsum[w];
      carry_s = carry + tot;
    }
    __syncthreads();
  }
  if (tid == 0) off[n] = carry_s;
}

__global__ __launch_bounds__(256) void fill_kernel(const void* __restrict__ ei, long long E,
                                                   int n, const int* __restrict__ flags,
                                                   int* __restrict__ pos, int* __restrict__ bsrc){
  int i = blockIdx.x * blockDim.x + threadIdx.x;
  if (i < E){
    int d = getedge(ei, E + i, flags[1], n);
    int s = getedge(ei, i, flags[1], n);
    int p = atomicAdd(&pos[d], 1);
    bsrc[p] = s;
  }
}

// ---------------- fused weight pre-transpose: Bt[N][K] (bf16) = W[K][N] ----------------
__global__ __launch_bounds__(256) void transpose_all_kernel(
    const void* __restrict__ Wp, const void* __restrict__ W0,
    const void* __restrict__ W1, const void* __restrict__ Wo,
    const int* __restrict__ flags,
    __hip_bfloat16* __restrict__ btp, __hip_bfloat16* __restrict__ bt0,
    __hip_bfloat16* __restrict__ bt1, __hip_bfloat16* __restrict__ bto)
{
  int f0 = flags[0];
  int o = blockIdx.x * 256 + threadIdx.x;
  const void* W; __hip_bfloat16* B; int K, N, loc;
  if (o < 65536)       { W = Wp; B = btp; K = 256; N = 256; loc = o; }
  else if (o < 131072) { W = W0; B = bt0; K = 256; N = 256; loc = o - 65536; }
  else if (o < 163840) { W = W1; B = bt1; K = 256; N = 128; loc = o - 131072; }
  else if (o < 180224) { W = Wo; B = bto; K = 128; N = 128; loc = o - 163840; }
  else return;
  int nn = loc / K, kk = loc - nn * K;
  B[loc] = __float2bfloat16(getf(W, (size_t)kk * N + nn, f0));
}

// ---------------- LDS-free direct-fragment MFMA GEMM ----------------
// C[M,N] = A[M,K] @ Bt^T (Bt is [N][K] bf16). Block = 128 rows x 128 cols, 4 waves.
// ALMODE: 0 none; 1 = fused attention logits, 4 heads of 64 (N=256, 2 y-blocks);
//         2 = fused logits, 1 head of 128 (N=128).
__device__ __forceinline__ bf16x8 pk8(f32x4 u, f32x4 w){
  bf16x8 r;
  r[0] = (__bf16)u.x; r[1] = (__bf16)u.y; r[2] = (__bf16)u.z; r[3] = (__bf16)u.w;
  r[4] = (__bf16)w.x; r[5] = (__bf16)w.y; r[6] = (__bf16)w.z; r[7] = (__bf16)w.w;
  return r;
}

template<int AMODE, bool OUTF, bool OUTB, bool RELU, bool BIAS, bool NORM, int ALMODE>
__global__ __launch_bounds__(256) void gemm_direct_kernel(
    const void* __restrict__ A, const __hip_bfloat16* __restrict__ Bt,
    const void* __restrict__ bias, const void* __restrict__ a_s, const void* __restrict__ a_d,
    const int* __restrict__ flags,
    float* __restrict__ Cf, __hip_bfloat16* __restrict__ Cb,
    float* __restrict__ als, float* __restrict__ ald,
    int M, int N, int K)
{
  const int f0 = flags[0];
  const bool af32 = (AMODE == 1) && (f0 != 0);
  int t = threadIdx.x;
  int wave = t >> 6, lane = t & 63;
  int q = lane >> 4, mi = lane & 15;
  int bm = blockIdx.x * 128 + wave * 32;
  int bn = blockIdx.y * 128;

  int r0 = min(bm + mi, M - 1);
  int r1 = min(bm + 16 + mi, M - 1);

  f32x4 acc[2][8] = {};

  if (af32){
    const float* Af = (const float*)A;
    const float* p0 = Af + (size_t)r0 * K + q * 8;
    const float* p1 = Af + (size_t)r1 * K + q * 8;
#pragma unroll 2
    for (int k0 = 0; k0 < K; k0 += 32){
      f32x4 u0 = *(const f32x4*)(p0 + k0);
      f32x4 w0 = *(const f32x4*)(p0 + k0 + 4);
      f32x4 u1 = *(const f32x4*)(p1 + k0);
      f32x4 w1 = *(const f32x4*)(p1 + k0 + 4);
      bf16x8 a0 = pk8(u0, w0);
      bf16x8 a1 = pk8(u1, w1);
#pragma unroll
      for (int nt = 0; nt < 8; nt++){
        bf16x8 b = *(const bf16x8*)(Bt + (size_t)(bn + nt * 16 + mi) * K + k0 + q * 8);
        acc[0][nt] = __builtin_amdgcn_mfma_f32_16x16x32_bf16(a0, b, acc[0][nt], 0, 0, 0);
        acc[1][nt] = __builtin_amdgcn_mfma_f32_16x16x32_bf16(a1, b, acc[1][nt], 0, 0, 0);
      }
    }
  } else {
    const __hip_bfloat16* Ab = (const __hip_bfloat16*)A;
    const __hip_bfloat16* p0 = Ab + (size_t)r0 * K + q * 8;
    const __hip_bfloat16* p1 = Ab + (size_t)r1 * K + q * 8;
#pragma unroll 2
    for (int k0 = 0; k0 < K; k0 += 32){
      bf16x8 a0 = *(const bf16x8*)(p0 + k0);
      bf16x8 a1 = *(const bf16x8*)(p1 + k0);
#pragma unroll
      for (int nt = 0; nt < 8; nt++){
        bf16x8 b = *(const bf16x8*)(Bt + (size_t)(bn + nt * 16 + mi) * K + k0 + q * 8);
        acc[0][nt] = __builtin_amdgcn_mfma_f32_16x16x32_bf16(a0, b, acc[0][nt], 0, 0, 0);
        acc[1][nt] = __builtin_amdgcn_mfma_f32_16x16x32_bf16(a1, b, acc[1][nt], 0, 0, 0);
      }
    }
  }

  float bv[8], asv[8], adv[8];
  if (BIAS){
#pragma unroll
    for (int nt = 0; nt < 8; nt++) bv[nt] = getf(bias, bn + nt * 16 + mi, f0);
  }
  if (ALMODE != 0){
#pragma unroll
    for (int nt = 0; nt < 8; nt++){
      asv[nt] = getf(a_s, bn + nt * 16 + mi, f0);
      adv[nt] = getf(a_d, bn + nt * 16 + mi, f0);
    }
  }
#pragma unroll
  for (int mt = 0; mt < 2; mt++){
#pragma unroll
    for (int r = 0; r < 4; r++){
      int row = bm + mt * 16 + q * 4 + r;
      float vv[8];
#pragma unroll
      for (int nt = 0; nt < 8; nt++){
        float v = acc[mt][nt][r];
        if (BIAS) v += bv[nt];
        if (RELU) v = fmaxf(v, 0.f);
        vv[nt] = v;
      }
      if (NORM){
        float ss = 0.f;
#pragma unroll
        for (int nt = 0; nt < 8; nt++) ss += vv[nt] * vv[nt];
        ss += __shfl_xor(ss, 1, 64);
        ss += __shfl_xor(ss, 2, 64);
        ss += __shfl_xor(ss, 4, 64);
        ss += __shfl_xor(ss, 8, 64);
        float inv = 1.f / fmaxf(sqrtf(ss), 1e-12f);
#pragma unroll
        for (int nt = 0; nt < 8; nt++) vv[nt] *= inv;
      }
      if (ALMODE == 1){
        // heads: cols bn..bn+63 -> h0 = blockIdx.y*2; bn+64..bn+127 -> h0+1
        float ps0 = 0.f, pd0 = 0.f, ps1 = 0.f, pd1 = 0.f;
#pragma unroll
        for (int nt = 0; nt < 4; nt++){ ps0 += vv[nt] * asv[nt]; pd0 += vv[nt] * adv[nt]; }
#pragma unroll
        for (int nt = 4; nt < 8; nt++){ ps1 += vv[nt] * asv[nt]; pd1 += vv[nt] * adv[nt]; }
#pragma unroll
        for (int m = 1; m < 16; m <<= 1){
          ps0 += __shfl_xor(ps0, m, 64); pd0 += __shfl_xor(pd0, m, 64);
          ps1 += __shfl_xor(ps1, m, 64); pd1 += __shfl_xor(pd1, m, 64);
        }
        if ((lane & 15) == 0 && row < M){
          int h0 = blockIdx.y * 2;
          als[(size_t)row * 4 + h0]     = ps0; ald[(size_t)row * 4 + h0]     = pd0;
          als[(size_t)row * 4 + h0 + 1] = ps1; ald[(size_t)row * 4 + h0 + 1] = pd1;
        }
      } else if (ALMODE == 2){
        float ps = 0.f, pd = 0.f;
#pragma unroll
        for (int nt = 0; nt < 8; nt++){ ps += vv[nt] * asv[nt]; pd += vv[nt] * adv[nt]; }
#pragma unroll
        for (int m = 1; m < 16; m <<= 1){
          ps += __shfl_xor(ps, m, 64); pd += __shfl_xor(pd, m, 64);
        }
        if ((lane & 15) == 0 && row < M){ als[row] = ps; ald[row] = pd; }
      }
      if (row < M){
#pragma unroll
        for (int nt = 0; nt < 8; nt++){
          int col = bn + nt * 16 + mi;
          size_t idx = (size_t)row * N + col;
          if (OUTF) Cf[idx] = vv[nt];
          if (OUTB) Cb[idx] = __float2bfloat16(vv[nt]);
        }
      }
    }
  }
}

#define FMA4(U, W) do { \
  m0 += (W) * __uint_as_float((U).x << 16); \
  m1 += (W) * __uint_as_float((U).x & 0xffff0000u); \
  m2 += (W) * __uint_as_float((U).y << 16); \
  m3 += (W) * __uint_as_float((U).y & 0xffff0000u); \
} while (0)

// ---------------- gather0: WAVE-per-node, H=4, C=64, fused edge weights ----------------
// lane owns 4 channels (ch = lane*4); head = lane>>4. w = exp(leaky(als[s]+ald[i]))
// computed in-register (als table is L2-hot). Residual read from bf16 h; in-place out.
__global__ __launch_bounds__(256) void gather0_kernel(
    const __hip_bfloat16* __restrict__ xw, const float* __restrict__ als, const float* __restrict__ ald,
    const int* __restrict__ bsrc, const int* __restrict__ off,
    const void* __restrict__ bias, const void* __restrict__ gamma,
    const void* __restrict__ beta, const int* __restrict__ flags,
    __hip_bfloat16* __restrict__ hbuf, int n)
{
  int f0 = flags[0];
  int t = threadIdx.x, wv = t >> 6, lane = t & 63;
  int i = blockIdx.x * 4 + wv;
  if (i >= n) return;
  int head = lane >> 4;
  int ch = lane * 4;
  int e0 = off[i], jend = off[i + 1];

  float m0 = 0.f, m1 = 0.f, m2 = 0.f, m3 = 0.f;

  float aldi = ald[(size_t)i * 4 + head];

  // self loop
  float se = als[(size_t)i * 4 + head] + aldi;
  se = (se > 0.f) ? se : 0.2f * se;
  float eself = __expf(se);
  {
    uint2 u = *(const uint2*)(xw + (size_t)i * 256 + ch);
    FMA4(u, eself);
  }
  float wacc = eself;

  // main loop: full quads
  int j = e0;
  for (; j + 3 < jend; j += 4){
    int s0 = bsrc[j], s1 = bsrc[j + 1], s2 = bsrc[j + 2], s3 = bsrc[j + 3];
    float l0 = als[(size_t)s0 * 4 + head] + aldi;
    float l1 = als[(size_t)s1 * 4 + head] + aldi;
    float l2 = als[(size_t)s2 * 4 + head] + aldi;
    float l3 = als[(size_t)s3 * 4 + head] + aldi;
    l0 = (l0 > 0.f) ? l0 : 0.2f * l0;
    l1 = (l1 > 0.f) ? l1 : 0.2f * l1;
    l2 = (l2 > 0.f) ? l2 : 0.2f * l2;
    l3 = (l3 > 0.f) ? l3 : 0.2f * l3;
    float w0 = __expf(l0), w1 = __expf(l1), w2 = __expf(l2), w3 = __expf(l3);
    uint2 U0 = *(const uint2*)(xw + (size_t)s0 * 256 + ch);
    uint2 U1 = *(const uint2*)(xw + (size_t)s1 * 256 + ch);
    uint2 U2 = *(const uint2*)(xw + (size_t)s2 * 256 + ch);
    uint2 U3 = *(const uint2*)(xw + (size_t)s3 * 256 + ch);
    wacc += w0 + w1 + w2 + w3;
    FMA4(U0, w0); FMA4(U1, w1); FMA4(U2, w2); FMA4(U3, w3);
  }
  for (; j < jend; j++){
    int s0 = bsrc[j];
    float l0 = als[(size_t)s0 * 4 + head] + aldi;
    l0 = (l0 > 0.f) ? l0 : 0.2f * l0;
    float w0 = __expf(l0);
    uint2 U0 = *(const uint2*)(xw + (size_t)s0 * 256 + ch);
    wacc += w0;
    FMA4(U0, w0);
  }

  float rl = 1.f / wacc;
  float v0 = m0 * rl + getf(bias, ch + 0, f0);
  float v1 = m1 * rl + getf(bias, ch + 1, f0);
  float v2 = m2 * rl + getf(bias, ch + 2, f0);
  float v3 = m3 * rl + getf(bias, ch + 3, f0);

  float mu = bfly_sum(v0 + v1 + v2 + v3) * (1.f / 256.f);
  float d0 = v0 - mu, d1 = v1 - mu, d2 = v2 - mu, d3 = v3 - mu;
  float var = bfly_sum(d0 * d0 + d1 * d1 + d2 * d2 + d3 * d3) * (1.f / 256.f);
  float rs = rsqrtf(var + 1e-5f);

  bf16x4 rb = *(const bf16x4*)(hbuf + (size_t)i * 256 + ch);
  float y0 = fmaxf(d0 * rs * getf(gamma, ch + 0, f0) + getf(beta, ch + 0, f0) + (float)rb[0], 0.f);
  float y1 = fmaxf(d1 * rs * getf(gamma, ch + 1, f0) + getf(beta, ch + 1, f0) + (float)rb[1], 0.f);
  float y2 = fmaxf(d2 * rs * getf(gamma, ch + 2, f0) + getf(beta, ch + 2, f0) + (float)rb[2], 0.f);
  float y3 = fmaxf(d3 * rs * getf(gamma, ch + 3, f0) + getf(beta, ch + 3, f0) + (float)rb[3], 0.f);

  bf16x4 o;
  o[0] = (__bf16)y0; o[1] = (__bf16)y1; o[2] = (__bf16)y2; o[3] = (__bf16)y3;
  *(bf16x4*)(hbuf + (size_t)i * 256 + ch) = o;
}

// ---------------- gather1: WAVE-per-node, H=1, C=128, fused edge weights ----------------
#define FMA2(U, W) do { \
  m0 += (W) * __uint_as_float((U) << 16); \
  m1 += (W) * __uint_as_float((U) & 0xffff0000u); \
} while (0)

__global__ __launch_bounds__(256) void gather1_kernel(
    const __hip_bfloat16* __restrict__ xw, const float* __restrict__ als, const float* __restrict__ ald,
    const int* __restrict__ bsrc, const int* __restrict__ off,
    const void* __restrict__ bias, const void* __restrict__ gamma,
    const void* __restrict__ beta, const int* __restrict__ flags,
    __hip_bfloat16* __restrict__ outb, int n)
{
  int f0 = flags[0];
  int t = threadIdx.x, wv = t >> 6, lane = t & 63;
  int i = blockIdx.x * 4 + wv;
  if (i >= n) return;
  int ch = lane * 2;
  int e0 = off[i], jend = off[i + 1];

  float m0 = 0.f, m1 = 0.f;

  float aldi = ald[i];
  float se = als[i] + aldi;
  se = (se > 0.f) ? se : 0.2f * se;
  float eself = __expf(se);
  {
    unsigned u = *(const unsigned*)(xw + (size_t)i * 128 + ch);
    FMA2(u, eself);
  }
  float wacc = eself;

  int j = e0;
  for (; j + 3 < jend; j += 4){
    int s0 = bsrc[j], s1 = bsrc[j + 1], s2 = bsrc[j + 2], s3 = bsrc[j + 3];
    float l0 = als[s0] + aldi, l1 = als[s1] + aldi, l2 = als[s2] + aldi, l3 = als[s3] + aldi;
    l0 = (l0 > 0.f) ? l0 : 0.2f * l0;
    l1 = (l1 > 0.f) ? l1 : 0.2f * l1;
    l2 = (l2 > 0.f) ? l2 : 0.2f * l2;
    l3 = (l3 > 0.f) ? l3 : 0.2f * l3;
    float w0 = __expf(l0), w1 = __expf(l1), w2 = __expf(l2), w3 = __expf(l3);
    unsigned U0 = *(const unsigned*)(xw + (size_t)s0 * 128 + ch);
    unsigned U1 = *(const unsigned*)(xw + (size_t)s1 * 128 + ch);
    unsigned U2 = *(const unsigned*)(xw + (size_t)s2 * 128 + ch);
    unsigned U3 = *(const unsigned*)(xw + (size_t)s3 * 128 + ch);
    wacc += w0 + w1 + w2 + w3;
    FMA2(U0, w0); FMA2(U1, w1); FMA2(U2, w2); FMA2(U3, w3);
  }
  for (; j < jend; j++){
    int s0 = bsrc[j];
    float l0 = als[s0] + aldi;
    l0 = (l0 > 0.f) ? l0 : 0.2f * l0;
    float w0 = __expf(l0);
    unsigned U0 = *(const unsigned*)(xw + (size_t)s0 * 128 + ch);
    wacc += w0;
    FMA2(U0, w0);
  }

  float rl = 1.f / wacc;
  float v0 = m0 * rl + getf(bias, ch + 0, f0);
  float v1 = m1 * rl + getf(bias, ch + 1, f0);

  float mu = bfly_sum(v0 + v1) * (1.f / 128.f);
  float d0 = v0 - mu, d1 = v1 - mu;
  float var = bfly_sum(d0 * d0 + d1 * d1) * (1.f / 128.f);
  float rs = rsqrtf(var + 1e-5f);

  float y0 = d0 * rs * getf(gamma, ch + 0, f0) + getf(beta, ch + 0, f0);
  float y1 = d1 * rs * getf(gamma, ch + 1, f0) + getf(beta, ch + 1, f0);

  bf16x2 o;
  o[0] = (__bf16)y0; o[1] = (__bf16)y1;
  *(bf16x2*)(outb + (size_t)i * 128 + ch) = o;
}

// ---------------- launch ----------------
extern "C" void kernel_launch(void* const* d_in, const int* in_sizes, int n_in,
                              void* d_out, int out_size, void* d_ws, size_t ws_size,
                              hipStream_t stream)
{
  const void* x   = d_in[0];
  const void* ei  = d_in[1];
  const void* Wp  = d_in[2];
  const void* bp  = d_in[3];
  const void* W0  = d_in[4];
  const void* as0 = d_in[5];
  const void* ad0 = d_in[6];
  const void* b0  = d_in[7];
  const void* W1  = d_in[8];
  const void* as1 = d_in[9];
  const void* ad1 = d_in[10];
  const void* b1  = d_in[11];
  const void* g0  = d_in[12];
  const void* be0 = d_in[13];
  const void* g1  = d_in[14];
  const void* be1 = d_in[15];
  const void* Wo  = d_in[16];
  const void* bo  = d_in[17];
  float* outp = (float*)d_out;

  const int n = in_sizes[0] / 256;   // 50000
  const int E = in_sizes[1] / 2;     // 800000

  char* w = (char*)d_ws;
  size_t SZ = (size_t)n * 256 * sizeof(float);
  __hip_bfloat16* h_bf  = (__hip_bfloat16*)w;             // h -> h1 -> h2 (bf16)
  __hip_bfloat16* xw_bf = (__hip_bfloat16*)(w + SZ / 2);  // xw0 -> xw1 (bf16)
  char* p = w + SZ;
  int* flags = (int*)p; p += 64;
  float* als0 = (float*)p; p += (size_t)n * 4 * sizeof(float);
  float* ald0 = (float*)p; p += (size_t)n * 4 * sizeof(float);
  float* als1 = (float*)p; p += (size_t)n * sizeof(float);
  float* ald1 = (float*)p; p += (size_t)n * sizeof(float);
  int* cnt  = (int*)p; p += (size_t)n * sizeof(int);
  int* offb = (int*)p; p += (size_t)(n + 4) * sizeof(int);   // 16B-aligned stride
  int* pos  = (int*)p; p += (size_t)n * sizeof(int);
  int* bsrc = (int*)p; p += (size_t)E * sizeof(int);
  p = (char*)(((uintptr_t)p + 15) & ~(uintptr_t)15);
  __hip_bfloat16* bt_p = (__hip_bfloat16*)p; p += (size_t)256 * 256 * 2;
  __hip_bfloat16* bt_0 = (__hip_bfloat16*)p; p += (size_t)256 * 256 * 2;
  __hip_bfloat16* bt_1 = (__hip_bfloat16*)p; p += (size_t)128 * 256 * 2;
  __hip_bfloat16* bt_o = (__hip_bfloat16*)p; p += (size_t)128 * 128 * 2;

  detect_kernel<<<1, 256, 0, stream>>>(x, ei, flags);

  transpose_all_kernel<<<704, 256, 0, stream>>>(Wp, W0, W1, Wo, flags, bt_p, bt_0, bt_1, bt_o);

  hipMemsetAsync(cnt, 0, (size_t)n * sizeof(int), stream);
  count_kernel<<<(E + 255) / 256, 256, 0, stream>>>(ei, E, n, flags, cnt);
  scan_kernel<<<1, 1024, 0, stream>>>(cnt, offb, pos, n);
  fill_kernel<<<(E + 255) / 256, 256, 0, stream>>>(ei, E, n, flags, pos, bsrc);

  int gm = (n + 127) / 128;
  int gn4 = (n + 3) / 4;

  // h = relu(x @ Wp + bp) -> bf16 only
  gemm_direct_kernel<1, false, true, true, true, false, 0><<<dim3(gm, 2), 256, 0, stream>>>(
      x, bt_p, bp, nullptr, nullptr, flags, nullptr, h_bf, nullptr, nullptr, n, 256, 256);
  // xw0 = h @ W0 (bf16) + fused als0/ald0
  gemm_direct_kernel<0, false, true, false, false, false, 1><<<dim3(gm, 2), 256, 0, stream>>>(
      h_bf, bt_0, nullptr, as0, ad0, flags, nullptr, xw_bf, als0, ald0, n, 256, 256);
  // layer-0 aggregate (fused edge weights) + b0 + LN + residual(bf16) + relu -> h1 in-place
  gather0_kernel<<<gn4, 256, 0, stream>>>(xw_bf, als0, ald0, bsrc, offb, b0, g0, be0,
                                          flags, h_bf, n);
  // xw1 = h1 @ W1 (bf16, n x 128) + fused als1/ald1
  gemm_direct_kernel<0, false, true, false, false, false, 2><<<dim3(gm, 1), 256, 0, stream>>>(
      h_bf, bt_1, nullptr, as1, ad1, flags, nullptr, xw_bf, als1, ald1, n, 128, 256);
  // layer-1 aggregate (fused edge weights) + b1 + LN -> h2 (bf16, into h_bf)
  gather1_kernel<<<gn4, 256, 0, stream>>>(xw_bf, als1, ald1, bsrc, offb, b1, g1, be1,
                                          flags, h_bf, n);
  // out = l2normalize(h2 @ Wo + bo), fused epilogue, direct to output
  gemm_direct_kernel<0, true, false, false, true, true, 0><<<dim3(gm, 1), 256, 0, stream>>>(
      h_bf, bt_o, bo, nullptr, nullptr, flags, outp, nullptr, nullptr, nullptr, n, 128, 128);
}